// Round 6
// baseline (578.254 us; speedup 1.0000x reference)
//
#include <hip/hip_runtime.h>

#define BS 4
#define SL 2048
#define NE 1024
#define NH 16
#define HD 64
#define N3 3072

typedef __attribute__((ext_vector_type(8))) __bf16 bf16x8;
typedef __attribute__((ext_vector_type(4))) float f32x4;
typedef unsigned short u16;

__device__ __forceinline__ u16 f2bf(float f) {
  union { float f; unsigned int u; } v; v.f = f;
  unsigned int r = v.u + 0x7FFFu + ((v.u >> 16) & 1u);
  return (u16)(r >> 16);
}
__device__ __forceinline__ u16 f2bf_rtz(float f) {
  union { float f; unsigned int u; } v; v.f = f;
  return (u16)(v.u >> 16);
}

// global -> LDS direct 16B copy. LDS dest is WAVE-UNIFORM base; HW adds
// lane*16. Global address is per-lane.
__device__ __forceinline__ void gld16(const void* g, void* l) {
#if __has_builtin(__builtin_amdgcn_global_load_lds)
  __builtin_amdgcn_global_load_lds(
      (const __attribute__((address_space(1))) unsigned int*)g,
      (__attribute__((address_space(3))) unsigned int*)l, 16, 0, 0);
#else
  *(int4*)((char*)l + (size_t)(threadIdx.x & 63) * 16) = *(const int4*)g;
#endif
}

// ---------------- x fp32 -> bf16 ----------------
__global__ void convert_x(const float* __restrict__ x, u16* __restrict__ xb) {
  int i = (blockIdx.x * 256 + threadIdx.x) * 8;
  float4 f0 = *(const float4*)(x + i);
  float4 f1 = *(const float4*)(x + i + 4);
  union { int4 v; u16 h[8]; } p;
  p.h[0] = f2bf(f0.x); p.h[1] = f2bf(f0.y);
  p.h[2] = f2bf(f0.z); p.h[3] = f2bf(f0.w);
  p.h[4] = f2bf(f1.x); p.h[5] = f2bf(f1.y);
  p.h[6] = f2bf(f1.z); p.h[7] = f2bf(f1.w);
  *(int4*)(xb + i) = p.v;
}

// ---------------- W transpose+convert: Wt[n*K+k] = bf16(W[k*N+n]) ----------
__global__ void transpose_w(const float* __restrict__ W, u16* __restrict__ Wt,
                            int K, int N) {
  __shared__ u16 tile[32][33];
  int bn = blockIdx.x * 32, bk = blockIdx.y * 32;
  int tx = threadIdx.x, ty = threadIdx.y;  // blockDim = (32, 8)
  for (int r = 0; r < 32; r += 8)
    tile[ty + r][tx] = f2bf(W[(size_t)(bk + ty + r) * N + bn + tx]);
  __syncthreads();
  for (int r = 0; r < 32; r += 8)
    Wt[(size_t)(bn + ty + r) * K + bk + tx] = tile[tx][ty + r];
}

// ---------------- GEMM: C[M,N] = A[M,K] @ Bt[N,K]^T + bias[N] ---------------
// A, Bt bf16 staged via global_load_lds width=16. C32: store fp32 else bf16.
template <int C32>
__global__ __launch_bounds__(256) void gemm_bt(
    const u16* __restrict__ A, const u16* __restrict__ Bt,
    const float* __restrict__ bias, void* __restrict__ C, int M, int N, int K,
    int lda) {
  __shared__ u16 As[128 * 32];
  __shared__ u16 Bs[128 * 32];

  const int tid = threadIdx.x;
  const int wave = tid >> 6, lane = tid & 63;
  const int lq = lane >> 4, lr = lane & 15;
  const int m0 = blockIdx.y * 128, n0 = blockIdx.x * 128;
  const int wm = (wave & 1) * 64, wn = (wave >> 1) * 64;

  const f32x4 fzero = {0.f, 0.f, 0.f, 0.f};
  f32x4 acc[4][4];
#pragma unroll
  for (int i = 0; i < 4; i++)
#pragma unroll
    for (int j = 0; j < 4; j++) acc[i][j] = fzero;

  for (int k0 = 0; k0 < K; k0 += 32) {
    __syncthreads();  // previous iteration's LDS readers are done
#pragma unroll
    for (int t = 0; t < 2; t++) {
      int chunk = wave * 2 + t;  // 1 KB chunk = 16 rows x 64 B
      const u16* ga = A + (size_t)(m0 + chunk * 16 + (lane >> 2)) * lda + k0 +
                      (lane & 3) * 8;
      gld16(ga, &As[chunk * 512]);
      const u16* gb = Bt + (size_t)(n0 + chunk * 16 + (lane >> 2)) * K + k0 +
                      (lane & 3) * 8;
      gld16(gb, &Bs[chunk * 512]);
    }
    __syncthreads();  // drains vmcnt (global_load_lds) + lgkm

    bf16x8 af[4], bfr[4];
#pragma unroll
    for (int i = 0; i < 4; i++)
      af[i] = *(const bf16x8*)&As[(wm + i * 16 + lr) * 32 + lq * 8];
#pragma unroll
    for (int j = 0; j < 4; j++)
      bfr[j] = *(const bf16x8*)&Bs[(wn + j * 16 + lr) * 32 + lq * 8];
#pragma unroll
    for (int i = 0; i < 4; i++)
#pragma unroll
      for (int j = 0; j < 4; j++)
        acc[i][j] = __builtin_amdgcn_mfma_f32_16x16x32_bf16(af[i], bfr[j],
                                                            acc[i][j], 0, 0, 0);
  }

  // Epilogue. C/D layout: col = lane&15, row = (lane>>4)*4 + reg.
#pragma unroll
  for (int j = 0; j < 4; j++) {
    int col = n0 + wn + j * 16 + lr;
    float bv = bias[col];
#pragma unroll
    for (int i = 0; i < 4; i++) {
#pragma unroll
      for (int r = 0; r < 4; r++) {
        int row = m0 + wm + i * 16 + lq * 4 + r;
        float val = acc[i][j][r] + bv;
        if (C32) ((float*)C)[(size_t)row * N + col] = val;
        else     ((u16*)C)[(size_t)row * N + col]   = f2bf(val);
      }
    }
  }
}

// ---------------- Flash attention (causal), paired q-tiles ----------------
// Block (bh, p): q-tiles {p, 31-p} of head bh&15, batch bh>>4 -> exactly 33
// half-tile steps per block (balanced). All 16 p-blocks of one (b,h) share
// linear-id mod 8 -> same XCD -> K/V L2 reuse.
// Pipelining (1 barrier/iter): K(kt+1) prefetched via async global_load_lds
// into the other LDS buffer right AFTER the barrier (compute hides it; next
// barrier's vmcnt drain completes it). V(kt+1) prefetched into STATIC named
// registers (no dynamic indexing -> no scratch!) and transposed into the
// other V buffer late in the iteration.
// LDS layouts (unpadded + XOR swizzle, 8-elem blocks):
//   K: [2][key(64) * 32 (d-half)], d-block swizzled by key&3  (4-way max)
//   V: [2][d(64) * 64 keys], key-block swizzled by d&7        (2-way, free)
//   P: [wave][row(16) * 64 keys], key-block swizzled by row&7 (2-way, free)
#define MFMA16(a, b, c) __builtin_amdgcn_mfma_f32_16x16x32_bf16(a, b, c, 0, 0, 0)

__device__ __forceinline__ void attn_step(const bf16x8& q0, const bf16x8& q1,
                                          const u16* __restrict__ Kb,
                                          const u16* __restrict__ Vb,
                                          u16* __restrict__ myP, bool diag,
                                          int w, int lq, int lr,
                                          f32x4 (&o)[4], float (&m_)[4],
                                          float (&l_)[4]) {
  const f32x4 fzero = {0.f, 0.f, 0.f, 0.f};
  const int swk = lr & 3, swv = lr & 7;
  f32x4 s[4];
#pragma unroll
  for (int j = 0; j < 4; j++) {
    int kr = j * 16 + lr;
    bf16x8 kf0 = *(const bf16x8*)&Kb[kr * 32 + ((lq ^ swk) * 8)];
    bf16x8 kf1 = *(const bf16x8*)&Kb[2048 + kr * 32 + ((lq ^ swk) * 8)];
    f32x4 z = MFMA16(q0, kf0, fzero);
    s[j] = MFMA16(q1, kf1, z);
  }
  if (diag) {  // local col = j*16+lr, local row = w*16+lq*4+r (raw scores)
#pragma unroll
    for (int j = 0; j < 4; j++)
#pragma unroll
      for (int r = 0; r < 4; r++)
        if (j * 16 + lr > w * 16 + lq * 4 + r) s[j][r] = -1e30f;
  }
  // softmax with scale folded into exp args (m tracked on RAW scores)
#pragma unroll
  for (int r = 0; r < 4; r++) {
    float mt = fmaxf(fmaxf(s[0][r], s[1][r]), fmaxf(s[2][r], s[3][r]));
#pragma unroll
    for (int off = 1; off < 16; off <<= 1)
      mt = fmaxf(mt, __shfl_xor(mt, off, 16));
    float mn = fmaxf(m_[r], mt);
    float alpha = __expf((m_[r] - mn) * 0.125f);
    m_[r] = mn;
    float psum = 0.f;
#pragma unroll
    for (int j = 0; j < 4; j++) {
      float pv = __expf((s[j][r] - mn) * 0.125f);
      s[j][r] = pv;
      psum += pv;
    }
    l_[r] = l_[r] * alpha + psum;  // per-lane partial; reduced in epilogue
#pragma unroll
    for (int j = 0; j < 4; j++) o[j][r] *= alpha;
  }
  // P: C-layout regs -> LDS (wave-private, swizzled) -> A-layout frags
#pragma unroll
  for (int j = 0; j < 4; j++) {
    int blk = j * 2 + (lr >> 3);
#pragma unroll
    for (int r = 0; r < 4; r++) {
      int row = lq * 4 + r;
      myP[row * 64 + ((blk ^ (row & 7)) * 8) + (lr & 7)] = f2bf_rtz(s[j][r]);
    }
  }
  __asm__ volatile("s_waitcnt lgkmcnt(0)" ::: "memory");  // wave-level fence
  bf16x8 pf0 = *(const bf16x8*)&myP[lr * 64 + ((lq ^ swv) * 8)];
  bf16x8 pf1 = *(const bf16x8*)&myP[lr * 64 + (((lq + 4) ^ swv) * 8)];
#pragma unroll
  for (int jd = 0; jd < 4; jd++) {
    int vr = jd * 16 + lr;
    bf16x8 vf0 = *(const bf16x8*)&Vb[vr * 64 + ((lq ^ swv) * 8)];
    bf16x8 vf1 = *(const bf16x8*)&Vb[vr * 64 + (((lq + 4) ^ swv) * 8)];
    o[jd] = MFMA16(pf0, vf0, o[jd]);
    o[jd] = MFMA16(pf1, vf1, o[jd]);
  }
}

__global__ __launch_bounds__(256, 4) void attn_paired(u16* __restrict__ qkv) {
  __shared__ u16 Ks[2][4096];    // [key*32 + swizzled d-blk], halves at +2048
  __shared__ u16 Vs[2][4096];    // [d*64 + swizzled key-blk]
  __shared__ u16 Ps[4][1024];    // per-wave P tile (halves reuse sequentially)

  const int tid = threadIdx.x;
  const int w = tid >> 6, lane = tid & 63;
  const int lq = lane >> 4, lr = lane & 15;
  const int bh = blockIdx.x, p = blockIdx.y;
  const int h = bh & (NH - 1), b = bh >> 4;
  const int qt0 = p, qt1 = (SL / 64 - 1) - p;

  u16* base = qkv + (size_t)b * SL * N3;
  const u16* kbase = base + NE + h * HD;      // K plane
  const u16* vbase = base + 2 * NE + h * HD;  // V plane

  // K staging via gld16: wave w stages chunks {2w, 2w+1}; chunk = half*4+kgrp
  const int kg_key = (lane >> 2);            // key within 16-group
  const int kg_blk = (lane & 3) ^ ((lane >> 2) & 3);  // swizzled d-block fetch
  // V staging: thread owns key=skey, d-chunks sd0, sd0+32
  const int skey = tid & 63, sd0 = (tid >> 6) * 8;
  const int vsw = (skey >> 3);               // key-block for swizzle

#define KPRE(buf, key0)                                                     \
  _Pragma("unroll") for (int t = 0; t < 2; t++) {                           \
    int chunk = w * 2 + t, half = chunk >> 2, kgrp = chunk & 3;             \
    const u16* g = kbase + (size_t)((key0) + kgrp * 16 + kg_key) * N3 +     \
                   half * 32 + kg_blk * 8;                                  \
    gld16(g, &Ks[buf][half * 2048 + kgrp * 512]);                           \
  }

  bf16x8 qf[2][2];
#pragma unroll
  for (int half = 0; half < 2; half++) {
    int qt = half ? qt1 : qt0;
    const u16* qrow = base + (size_t)(qt * 64 + w * 16 + lr) * N3 + h * HD;
    qf[half][0] = *(const bf16x8*)(qrow + lq * 8);
    qf[half][1] = *(const bf16x8*)(qrow + 32 + lq * 8);
  }

  const f32x4 fzero = {0.f, 0.f, 0.f, 0.f};
  f32x4 o[2][4];
  float m_[2][4], l_[2][4];
#pragma unroll
  for (int half = 0; half < 2; half++)
#pragma unroll
    for (int r = 0; r < 4; r++) {
      o[half][r] = fzero;
      m_[half][r] = -1e30f;
      l_[half][r] = 0.f;
    }

  // ---- stage tile 0: K via gld16, V via regs -> swizzled LDS
  KPRE(0, 0);
  {
    const u16* vr = vbase + (size_t)skey * N3 + sd0;
    int4 vA = *(const int4*)vr;
    int4 vB = *(const int4*)(vr + 32);
    union { int4 v; u16 u[8]; } t0, t1;
    t0.v = vA; t1.v = vB;
#pragma unroll
    for (int j = 0; j < 8; j++) {
      Vs[0][(sd0 + j) * 64 + ((vsw ^ j) * 8) + (skey & 7)] = t0.u[j];
      Vs[0][(sd0 + 32 + j) * 64 + ((vsw ^ j) * 8) + (skey & 7)] = t1.u[j];
    }
  }

  const int ktend = qt1 + 1;
  for (int kt = 0; kt < ktend; kt++) {
    __syncthreads();  // drains gld16(kt) + makes V(kt) writes visible
    const int nbuf = (kt + 1) & 1;
    int4 vA, vB;                       // static names -> real registers
    const bool pre = (kt + 1 < ktend);
    if (pre) {
      KPRE(nbuf, (kt + 1) * 64);       // async; lands by next barrier
      const u16* vr = vbase + (size_t)((kt + 1) * 64 + skey) * N3 + sd0;
      vA = *(const int4*)vr;
      vB = *(const int4*)(vr + 32);
    }

    const u16* Kb = &Ks[kt & 1][0];
    const u16* Vb = &Vs[kt & 1][0];
    attn_step(qf[1][0], qf[1][1], Kb, Vb, &Ps[w][0], kt == qt1, w, lq, lr,
              o[1], m_[1], l_[1]);
    if (kt <= qt0)
      attn_step(qf[0][0], qf[0][1], Kb, Vb, &Ps[w][0], kt == qt0, w, lq, lr,
                o[0], m_[0], l_[0]);

    if (pre) {  // transpose V(kt+1) into the other buffer (no readers yet)
      union { int4 v; u16 u[8]; } t0, t1;
      t0.v = vA; t1.v = vB;
#pragma unroll
      for (int j = 0; j < 8; j++) {
        Vs[nbuf][(sd0 + j) * 64 + ((vsw ^ j) * 8) + (skey & 7)] = t0.u[j];
        Vs[nbuf][(sd0 + 32 + j) * 64 + ((vsw ^ j) * 8) + (skey & 7)] = t1.u[j];
      }
    }
  }

  // epilogue: reduce per-lane l partials across the 16 col-lanes, write Y
  // over the Q slot (rows are block-private -> in-place safe)
#pragma unroll
  for (int half = 0; half < 2; half++) {
    int qt = half ? qt1 : qt0;
#pragma unroll
    for (int r = 0; r < 4; r++) {
      float lsum = l_[half][r];
#pragma unroll
      for (int off = 1; off < 16; off <<= 1) lsum += __shfl_xor(lsum, off, 16);
      float inv = 1.0f / lsum;
      int srow = qt * 64 + w * 16 + lq * 4 + r;
      u16* yrow = base + (size_t)srow * N3 + h * HD;
#pragma unroll
      for (int j = 0; j < 4; j++) yrow[j * 16 + lr] = f2bf(o[half][j][r] * inv);
    }
  }
}

// ---------------- host launch ----------------
extern "C" void kernel_launch(void* const* d_in, const int* in_sizes, int n_in,
                              void* d_out, int out_size, void* d_ws,
                              size_t ws_size, hipStream_t stream) {
  // inputs (fp32 / int32): x, mask(ignored - analytic causal), Wqkv, bqkv,
  // Wo, bo
  const float* x    = (const float*)d_in[0];
  const float* Wqkv = (const float*)d_in[2];
  const float* bqkv = (const float*)d_in[3];
  const float* Wo   = (const float*)d_in[4];
  const float* bo   = (const float*)d_in[5];

  u16* WqkvT  = (u16*)d_ws;                       // [3072,1024] bf16
  u16* WoT    = WqkvT + (size_t)N3 * NE;          // [1024,1024] bf16
  u16* xb     = WoT + (size_t)NE * NE;            // [8192,1024] bf16
  u16* qkvbuf = xb + (size_t)BS * SL * NE;        // [8192,3072] bf16

  convert_x<<<(BS * SL * NE) / (256 * 8), 256, 0, stream>>>(x, xb);
  transpose_w<<<dim3(N3 / 32, NE / 32), dim3(32, 8), 0, stream>>>(Wqkv, WqkvT,
                                                                  NE, N3);
  transpose_w<<<dim3(NE / 32, NE / 32), dim3(32, 8), 0, stream>>>(Wo, WoT, NE,
                                                                  NE);
  gemm_bt<0><<<dim3(N3 / 128, (BS * SL) / 128), 256, 0, stream>>>(
      xb, WqkvT, bqkv, qkvbuf, BS * SL, N3, NE, NE);
  attn_paired<<<dim3(BS * NH, SL / 128), 256, 0, stream>>>(qkvbuf);
  gemm_bt<1><<<dim3(NE / 128, (BS * SL) / 128), 256, 0, stream>>>(
      qkvbuf, WoT, bo, d_out, BS * SL, NE, NE, N3);
}

// Round 7
// 350.566 us; speedup vs baseline: 1.6495x; 1.6495x over previous
//
#include <hip/hip_runtime.h>

#define BS 4
#define SL 2048
#define NE 1024
#define NH 16
#define HD 64
#define N3 3072

typedef __attribute__((ext_vector_type(8))) __bf16 bf16x8;
typedef __attribute__((ext_vector_type(4))) float f32x4;
typedef unsigned short u16;

__device__ __forceinline__ u16 f2bf(float f) {
  union { float f; unsigned int u; } v; v.f = f;
  unsigned int r = v.u + 0x7FFFu + ((v.u >> 16) & 1u);
  return (u16)(r >> 16);
}
__device__ __forceinline__ u16 f2bf_rtz(float f) {
  union { float f; unsigned int u; } v; v.f = f;
  return (u16)(v.u >> 16);
}

// global -> LDS direct 16B copy. LDS dest is WAVE-UNIFORM base; HW adds
// lane*16. Global address is per-lane.
__device__ __forceinline__ void gld16(const void* g, void* l) {
#if __has_builtin(__builtin_amdgcn_global_load_lds)
  __builtin_amdgcn_global_load_lds(
      (const __attribute__((address_space(1))) unsigned int*)g,
      (__attribute__((address_space(3))) unsigned int*)l, 16, 0, 0);
#else
  *(int4*)((char*)l + (size_t)(threadIdx.x & 63) * 16) = *(const int4*)g;
#endif
}

// ---------------- x fp32 -> bf16 ----------------
__global__ void convert_x(const float* __restrict__ x, u16* __restrict__ xb) {
  int i = (blockIdx.x * 256 + threadIdx.x) * 8;
  float4 f0 = *(const float4*)(x + i);
  float4 f1 = *(const float4*)(x + i + 4);
  union { int4 v; u16 h[8]; } p;
  p.h[0] = f2bf(f0.x); p.h[1] = f2bf(f0.y);
  p.h[2] = f2bf(f0.z); p.h[3] = f2bf(f0.w);
  p.h[4] = f2bf(f1.x); p.h[5] = f2bf(f1.y);
  p.h[6] = f2bf(f1.z); p.h[7] = f2bf(f1.w);
  *(int4*)(xb + i) = p.v;
}

// ---------------- W transpose+convert: Wt[n*K+k] = bf16(W[k*N+n]) ----------
__global__ void transpose_w(const float* __restrict__ W, u16* __restrict__ Wt,
                            int K, int N) {
  __shared__ u16 tile[32][33];
  int bn = blockIdx.x * 32, bk = blockIdx.y * 32;
  int tx = threadIdx.x, ty = threadIdx.y;  // blockDim = (32, 8)
  for (int r = 0; r < 32; r += 8)
    tile[ty + r][tx] = f2bf(W[(size_t)(bk + ty + r) * N + bn + tx]);
  __syncthreads();
  for (int r = 0; r < 32; r += 8)
    Wt[(size_t)(bn + ty + r) * K + bk + tx] = tile[tx][ty + r];
}

// ---------------- GEMM: C[M,N] = A[M,K] @ Bt[N,K]^T + bias[N] ---------------
// A, Bt bf16 staged via global_load_lds width=16. C32: store fp32 else bf16.
template <int C32>
__global__ __launch_bounds__(256) void gemm_bt(
    const u16* __restrict__ A, const u16* __restrict__ Bt,
    const float* __restrict__ bias, void* __restrict__ C, int M, int N, int K,
    int lda) {
  __shared__ u16 As[128 * 32];
  __shared__ u16 Bs[128 * 32];

  const int tid = threadIdx.x;
  const int wave = tid >> 6, lane = tid & 63;
  const int lq = lane >> 4, lr = lane & 15;
  const int m0 = blockIdx.y * 128, n0 = blockIdx.x * 128;
  const int wm = (wave & 1) * 64, wn = (wave >> 1) * 64;

  const f32x4 fzero = {0.f, 0.f, 0.f, 0.f};
  f32x4 acc[4][4];
#pragma unroll
  for (int i = 0; i < 4; i++)
#pragma unroll
    for (int j = 0; j < 4; j++) acc[i][j] = fzero;

  for (int k0 = 0; k0 < K; k0 += 32) {
    __syncthreads();  // previous iteration's LDS readers are done
#pragma unroll
    for (int t = 0; t < 2; t++) {
      int chunk = wave * 2 + t;  // 1 KB chunk = 16 rows x 64 B
      const u16* ga = A + (size_t)(m0 + chunk * 16 + (lane >> 2)) * lda + k0 +
                      (lane & 3) * 8;
      gld16(ga, &As[chunk * 512]);
      const u16* gb = Bt + (size_t)(n0 + chunk * 16 + (lane >> 2)) * K + k0 +
                      (lane & 3) * 8;
      gld16(gb, &Bs[chunk * 512]);
    }
    __syncthreads();  // drains vmcnt (global_load_lds) + lgkm

    bf16x8 af[4], bfr[4];
#pragma unroll
    for (int i = 0; i < 4; i++)
      af[i] = *(const bf16x8*)&As[(wm + i * 16 + lr) * 32 + lq * 8];
#pragma unroll
    for (int j = 0; j < 4; j++)
      bfr[j] = *(const bf16x8*)&Bs[(wn + j * 16 + lr) * 32 + lq * 8];
#pragma unroll
    for (int i = 0; i < 4; i++)
#pragma unroll
      for (int j = 0; j < 4; j++)
        acc[i][j] = __builtin_amdgcn_mfma_f32_16x16x32_bf16(af[i], bfr[j],
                                                            acc[i][j], 0, 0, 0);
  }

  // Epilogue. C/D layout: col = lane&15, row = (lane>>4)*4 + reg.
#pragma unroll
  for (int j = 0; j < 4; j++) {
    int col = n0 + wn + j * 16 + lr;
    float bv = bias[col];
#pragma unroll
    for (int i = 0; i < 4; i++) {
#pragma unroll
      for (int r = 0; r < 4; r++) {
        int row = m0 + wm + i * 16 + lq * 4 + r;
        float val = acc[i][j][r] + bv;
        if (C32) ((float*)C)[(size_t)row * N + col] = val;
        else     ((u16*)C)[(size_t)row * N + col]   = f2bf(val);
      }
    }
  }
}

// ---------------- Flash attention (causal), paired q-tiles ----------------
// Block (bh, p): q-tiles {p, 31-p} of head bh&15, batch bh>>4 -> exactly 33
// half-tile steps per block (perfect balance). All 16 p-blocks of one (b,h)
// share linear-id mod 8 -> same XCD -> K/V L2 reuse.
// __launch_bounds__(256,3): 170-VGPR cap. (256,4)'s 128-cap forced scratch
// spill (r5/r6: 300+ MB phantom WRITE) that cost 2x kernel time.
#define KSTR 72  // 64 + 8 pad elems (rows 16B aligned)
#define MFMA16(a, b, c) __builtin_amdgcn_mfma_f32_16x16x32_bf16(a, b, c, 0, 0, 0)

__device__ __forceinline__ void attn_step(const bf16x8& q0, const bf16x8& q1,
                                          const u16* __restrict__ Ks,
                                          const u16* __restrict__ Vs,
                                          u16* __restrict__ myP, bool diag,
                                          int w, int lq, int lr,
                                          f32x4 (&o)[4], float (&m_)[4],
                                          float (&l_)[4]) {
  const f32x4 fzero = {0.f, 0.f, 0.f, 0.f};
  f32x4 s[4];
#pragma unroll
  for (int j = 0; j < 4; j++) {
    bf16x8 kf0 = *(const bf16x8*)&Ks[(j * 16 + lr) * KSTR + lq * 8];
    bf16x8 kf1 = *(const bf16x8*)&Ks[(j * 16 + lr) * KSTR + 32 + lq * 8];
    f32x4 z = MFMA16(q0, kf0, fzero);
    s[j] = MFMA16(q1, kf1, z);
  }
  if (diag) {  // local col = j*16+lr, local row = w*16+lq*4+r (raw scores)
#pragma unroll
    for (int j = 0; j < 4; j++)
#pragma unroll
      for (int r = 0; r < 4; r++)
        if (j * 16 + lr > w * 16 + lq * 4 + r) s[j][r] = -1e30f;
  }
  // online softmax on RAW scores; 1/sqrt(HD)=0.125 folded into exp args
#pragma unroll
  for (int r = 0; r < 4; r++) {
    float mt = fmaxf(fmaxf(s[0][r], s[1][r]), fmaxf(s[2][r], s[3][r]));
#pragma unroll
    for (int off = 1; off < 16; off <<= 1)
      mt = fmaxf(mt, __shfl_xor(mt, off, 16));
    float mn = fmaxf(m_[r], mt);
    float alpha = __expf((m_[r] - mn) * 0.125f);
    m_[r] = mn;
    float psum = 0.f;
#pragma unroll
    for (int j = 0; j < 4; j++) {
      float pv = __expf((s[j][r] - mn) * 0.125f);
      s[j][r] = pv;
      psum += pv;
    }
    l_[r] = l_[r] * alpha + psum;  // per-lane partial; reduced in epilogue
#pragma unroll
    for (int j = 0; j < 4; j++) o[j][r] *= alpha;
  }
  // P: C-layout regs -> LDS (wave-private) -> A-layout frags
#pragma unroll
  for (int j = 0; j < 4; j++)
#pragma unroll
    for (int r = 0; r < 4; r++)
      myP[(lq * 4 + r) * KSTR + j * 16 + lr] = f2bf_rtz(s[j][r]);
  __asm__ volatile("s_waitcnt lgkmcnt(0)" ::: "memory");  // wave-level fence
  bf16x8 pf0 = *(const bf16x8*)&myP[lr * KSTR + lq * 8];
  bf16x8 pf1 = *(const bf16x8*)&myP[lr * KSTR + 32 + lq * 8];
#pragma unroll
  for (int jd = 0; jd < 4; jd++) {
    bf16x8 vf0 = *(const bf16x8*)&Vs[(jd * 16 + lr) * KSTR + lq * 8];
    bf16x8 vf1 = *(const bf16x8*)&Vs[(jd * 16 + lr) * KSTR + 32 + lq * 8];
    o[jd] = MFMA16(pf0, vf0, o[jd]);
    o[jd] = MFMA16(pf1, vf1, o[jd]);
  }
}

__global__ __launch_bounds__(256, 3) void attn_paired(u16* __restrict__ qkv) {
  __shared__ u16 Ks[64 * KSTR];
  __shared__ u16 Vs[64 * KSTR];
  __shared__ u16 Ps[4][16 * KSTR];  // per-wave; halves use it sequentially

  const int tid = threadIdx.x;
  const int w = tid >> 6, lane = tid & 63;
  const int lq = lane >> 4, lr = lane & 15;
  const int bh = blockIdx.x, p = blockIdx.y;
  const int h = bh & (NH - 1), b = bh >> 4;
  const int qt0 = p, qt1 = (SL / 64 - 1) - p;

  u16* base = qkv + (size_t)b * SL * N3;

  bf16x8 qf[2][2];
#pragma unroll
  for (int half = 0; half < 2; half++) {
    int qt = half ? qt1 : qt0;
    const u16* qrow = base + (size_t)(qt * 64 + w * 16 + lr) * N3 + h * HD;
    qf[half][0] = *(const bf16x8*)(qrow + lq * 8);
    qf[half][1] = *(const bf16x8*)(qrow + 32 + lq * 8);
  }

  const f32x4 fzero = {0.f, 0.f, 0.f, 0.f};
  f32x4 o[2][4];
  float m_[2][4], l_[2][4];
#pragma unroll
  for (int half = 0; half < 2; half++)
#pragma unroll
    for (int r = 0; r < 4; r++) {
      o[half][r] = fzero;
      m_[half][r] = -1e30f;
      l_[half][r] = 0.f;
    }

  const int ktend = qt1 + 1;
  for (int kt = 0; kt < ktend; kt++) {
    const int key0 = kt * 64;
    __syncthreads();
    for (int c = tid; c < 512; c += 256) {
      int key = c & 63, d0 = (c >> 6) * 8;
      const u16* krow = base + (size_t)(key0 + key) * N3 + NE + h * HD;
      *(int4*)&Ks[key * KSTR + d0] = *(const int4*)(krow + d0);
      const u16* vrow = base + (size_t)(key0 + key) * N3 + 2 * NE + h * HD;
      union { int4 v; u16 u[8]; } tmp;
      tmp.v = *(const int4*)(vrow + d0);
#pragma unroll
      for (int j = 0; j < 8; j++) Vs[(d0 + j) * KSTR + key] = tmp.u[j];
    }
    __syncthreads();

    attn_step(qf[1][0], qf[1][1], Ks, Vs, &Ps[w][0], kt == qt1, w, lq, lr,
              o[1], m_[1], l_[1]);
    if (kt <= qt0)
      attn_step(qf[0][0], qf[0][1], Ks, Vs, &Ps[w][0], kt == qt0, w, lq, lr,
                o[0], m_[0], l_[0]);
  }

  // epilogue: reduce per-lane l partials across the 16 col-lanes, write Y
  // over the Q slot (rows are block-private -> in-place safe)
#pragma unroll
  for (int half = 0; half < 2; half++) {
    int qt = half ? qt1 : qt0;
#pragma unroll
    for (int r = 0; r < 4; r++) {
      float lsum = l_[half][r];
#pragma unroll
      for (int off = 1; off < 16; off <<= 1) lsum += __shfl_xor(lsum, off, 16);
      float inv = 1.0f / lsum;
      int srow = qt * 64 + w * 16 + lq * 4 + r;
      u16* yrow = base + (size_t)srow * N3 + h * HD;
#pragma unroll
      for (int j = 0; j < 4; j++) yrow[j * 16 + lr] = f2bf(o[half][j][r] * inv);
    }
  }
}

// ---------------- host launch ----------------
extern "C" void kernel_launch(void* const* d_in, const int* in_sizes, int n_in,
                              void* d_out, int out_size, void* d_ws,
                              size_t ws_size, hipStream_t stream) {
  // inputs (fp32 / int32): x, mask(ignored - analytic causal), Wqkv, bqkv,
  // Wo, bo
  const float* x    = (const float*)d_in[0];
  const float* Wqkv = (const float*)d_in[2];
  const float* bqkv = (const float*)d_in[3];
  const float* Wo   = (const float*)d_in[4];
  const float* bo   = (const float*)d_in[5];

  u16* WqkvT  = (u16*)d_ws;                       // [3072,1024] bf16
  u16* WoT    = WqkvT + (size_t)N3 * NE;          // [1024,1024] bf16
  u16* xb     = WoT + (size_t)NE * NE;            // [8192,1024] bf16
  u16* qkvbuf = xb + (size_t)BS * SL * NE;        // [8192,3072] bf16

  convert_x<<<(BS * SL * NE) / (256 * 8), 256, 0, stream>>>(x, xb);
  transpose_w<<<dim3(N3 / 32, NE / 32), dim3(32, 8), 0, stream>>>(Wqkv, WqkvT,
                                                                  NE, N3);
  transpose_w<<<dim3(NE / 32, NE / 32), dim3(32, 8), 0, stream>>>(Wo, WoT, NE,
                                                                  NE);
  gemm_bt<0><<<dim3(N3 / 128, (BS * SL) / 128), 256, 0, stream>>>(
      xb, WqkvT, bqkv, qkvbuf, BS * SL, N3, NE, NE);
  attn_paired<<<dim3(BS * NH, SL / 128), 256, 0, stream>>>(qkvbuf);
  gemm_bt<1><<<dim3(NE / 128, (BS * SL) / 128), 256, 0, stream>>>(
      qkvbuf, WoT, bo, d_out, BS * SL, NE, NE, N3);
}

// Round 8
// 342.322 us; speedup vs baseline: 1.6892x; 1.0241x over previous
//
#include <hip/hip_runtime.h>

#define BS 4
#define SL 2048
#define NE 1024
#define NH 16
#define HD 64
#define N3 3072

typedef __attribute__((ext_vector_type(8))) __bf16 bf16x8;
typedef __attribute__((ext_vector_type(4))) float f32x4;
typedef unsigned short u16;

__device__ __forceinline__ u16 f2bf(float f) {
  union { float f; unsigned int u; } v; v.f = f;
  unsigned int r = v.u + 0x7FFFu + ((v.u >> 16) & 1u);
  return (u16)(r >> 16);
}
__device__ __forceinline__ u16 f2bf_rtz(float f) {
  union { float f; unsigned int u; } v; v.f = f;
  return (u16)(v.u >> 16);
}

// global -> LDS direct 16B copy. LDS dest is WAVE-UNIFORM base; HW adds
// lane*16. Global address is per-lane.
__device__ __forceinline__ void gld16(const void* g, void* l) {
#if __has_builtin(__builtin_amdgcn_global_load_lds)
  __builtin_amdgcn_global_load_lds(
      (const __attribute__((address_space(1))) unsigned int*)g,
      (__attribute__((address_space(3))) unsigned int*)l, 16, 0, 0);
#else
  *(int4*)((char*)l + (size_t)(threadIdx.x & 63) * 16) = *(const int4*)g;
#endif
}

// ---------------- x fp32 -> bf16 ----------------
__global__ void convert_x(const float* __restrict__ x, u16* __restrict__ xb) {
  int i = (blockIdx.x * 256 + threadIdx.x) * 8;
  float4 f0 = *(const float4*)(x + i);
  float4 f1 = *(const float4*)(x + i + 4);
  union { int4 v; u16 h[8]; } p;
  p.h[0] = f2bf(f0.x); p.h[1] = f2bf(f0.y);
  p.h[2] = f2bf(f0.z); p.h[3] = f2bf(f0.w);
  p.h[4] = f2bf(f1.x); p.h[5] = f2bf(f1.y);
  p.h[6] = f2bf(f1.z); p.h[7] = f2bf(f1.w);
  *(int4*)(xb + i) = p.v;
}

// ---------------- W transpose+convert: Wt[n*K+k] = bf16(W[k*N+n]) ----------
__global__ void transpose_w(const float* __restrict__ W, u16* __restrict__ Wt,
                            int K, int N) {
  __shared__ u16 tile[32][33];
  int bn = blockIdx.x * 32, bk = blockIdx.y * 32;
  int tx = threadIdx.x, ty = threadIdx.y;  // blockDim = (32, 8)
  for (int r = 0; r < 32; r += 8)
    tile[ty + r][tx] = f2bf(W[(size_t)(bk + ty + r) * N + bn + tx]);
  __syncthreads();
  for (int r = 0; r < 32; r += 8)
    Wt[(size_t)(bn + ty + r) * K + bk + tx] = tile[tx][ty + r];
}

// ---------------- GEMM: C[M,N] = A[M,K] @ Bt[N,K]^T + bias[N] ---------------
// A, Bt bf16 staged via global_load_lds width=16. C32: store fp32 else bf16.
template <int C32>
__global__ __launch_bounds__(256) void gemm_bt(
    const u16* __restrict__ A, const u16* __restrict__ Bt,
    const float* __restrict__ bias, void* __restrict__ C, int M, int N, int K,
    int lda) {
  __shared__ u16 As[128 * 32];
  __shared__ u16 Bs[128 * 32];

  const int tid = threadIdx.x;
  const int wave = tid >> 6, lane = tid & 63;
  const int lq = lane >> 4, lr = lane & 15;
  const int m0 = blockIdx.y * 128, n0 = blockIdx.x * 128;
  const int wm = (wave & 1) * 64, wn = (wave >> 1) * 64;

  const f32x4 fzero = {0.f, 0.f, 0.f, 0.f};
  f32x4 acc[4][4];
#pragma unroll
  for (int i = 0; i < 4; i++)
#pragma unroll
    for (int j = 0; j < 4; j++) acc[i][j] = fzero;

  for (int k0 = 0; k0 < K; k0 += 32) {
    __syncthreads();  // previous iteration's LDS readers are done
#pragma unroll
    for (int t = 0; t < 2; t++) {
      int chunk = wave * 2 + t;  // 1 KB chunk = 16 rows x 64 B
      const u16* ga = A + (size_t)(m0 + chunk * 16 + (lane >> 2)) * lda + k0 +
                      (lane & 3) * 8;
      gld16(ga, &As[chunk * 512]);
      const u16* gb = Bt + (size_t)(n0 + chunk * 16 + (lane >> 2)) * K + k0 +
                      (lane & 3) * 8;
      gld16(gb, &Bs[chunk * 512]);
    }
    __syncthreads();  // drains vmcnt (global_load_lds) + lgkm

    bf16x8 af[4], bfr[4];
#pragma unroll
    for (int i = 0; i < 4; i++)
      af[i] = *(const bf16x8*)&As[(wm + i * 16 + lr) * 32 + lq * 8];
#pragma unroll
    for (int j = 0; j < 4; j++)
      bfr[j] = *(const bf16x8*)&Bs[(wn + j * 16 + lr) * 32 + lq * 8];
#pragma unroll
    for (int i = 0; i < 4; i++)
#pragma unroll
      for (int j = 0; j < 4; j++)
        acc[i][j] = __builtin_amdgcn_mfma_f32_16x16x32_bf16(af[i], bfr[j],
                                                            acc[i][j], 0, 0, 0);
  }

  // Epilogue. C/D layout: col = lane&15, row = (lane>>4)*4 + reg.
#pragma unroll
  for (int j = 0; j < 4; j++) {
    int col = n0 + wn + j * 16 + lr;
    float bv = bias[col];
#pragma unroll
    for (int i = 0; i < 4; i++) {
#pragma unroll
      for (int r = 0; r < 4; r++) {
        int row = m0 + wm + i * 16 + lq * 4 + r;
        float val = acc[i][j][r] + bv;
        if (C32) ((float*)C)[(size_t)row * N + col] = val;
        else     ((u16*)C)[(size_t)row * N + col]   = f2bf(val);
      }
    }
  }
}

// ---------------- Flash attention (causal), paired q-tiles ----------------
// Block (bh, p): q-tiles {p, 31-p} of head bh&15, batch bh>>4 -> exactly 33
// half-tile steps per block (perfect balance). All 16 p-blocks of one (b,h)
// share linear-id mod 8 -> same XCD -> K/V L2 reuse (r7: FETCH 34.6MB vs
// 540MB demand).
// K/V(kt+1) prefetched into STATIC NAMED int4 regs (k0/k1/v0/v1 — never a
// dynamically-indexed array: r5's scratch-spill lesson) right after the
// LDS-ready barrier; consumed at the next iteration's LDS-write. The whole
// compute phase hides the global load latency.
// __launch_bounds__(256,4): 2nd arg = blocks/CU at 256 threads; grid gives
// 4/CU. VGPR cap 128 >= ~96 used. (256,3) was self-capping occupancy at 3.
#define KSTR 72  // 64 + 8 pad elems (rows 16B aligned)
#define MFMA16(a, b, c) __builtin_amdgcn_mfma_f32_16x16x32_bf16(a, b, c, 0, 0, 0)

__device__ __forceinline__ void attn_step(const bf16x8& q0, const bf16x8& q1,
                                          const u16* __restrict__ Ks,
                                          const u16* __restrict__ Vs,
                                          u16* __restrict__ myP, bool diag,
                                          int w, int lq, int lr,
                                          f32x4 (&o)[4], float (&m_)[4],
                                          float (&l_)[4]) {
  const f32x4 fzero = {0.f, 0.f, 0.f, 0.f};
  f32x4 s[4];
#pragma unroll
  for (int j = 0; j < 4; j++) {
    bf16x8 kf0 = *(const bf16x8*)&Ks[(j * 16 + lr) * KSTR + lq * 8];
    bf16x8 kf1 = *(const bf16x8*)&Ks[(j * 16 + lr) * KSTR + 32 + lq * 8];
    f32x4 z = MFMA16(q0, kf0, fzero);
    s[j] = MFMA16(q1, kf1, z);
  }
  if (diag) {  // local col = j*16+lr, local row = w*16+lq*4+r (raw scores)
#pragma unroll
    for (int j = 0; j < 4; j++)
#pragma unroll
      for (int r = 0; r < 4; r++)
        if (j * 16 + lr > w * 16 + lq * 4 + r) s[j][r] = -1e30f;
  }
  // online softmax on RAW scores; 1/sqrt(HD)=0.125 folded into exp args
#pragma unroll
  for (int r = 0; r < 4; r++) {
    float mt = fmaxf(fmaxf(s[0][r], s[1][r]), fmaxf(s[2][r], s[3][r]));
#pragma unroll
    for (int off = 1; off < 16; off <<= 1)
      mt = fmaxf(mt, __shfl_xor(mt, off, 16));
    float mn = fmaxf(m_[r], mt);
    float alpha = __expf((m_[r] - mn) * 0.125f);
    m_[r] = mn;
    float psum = 0.f;
#pragma unroll
    for (int j = 0; j < 4; j++) {
      float pv = __expf((s[j][r] - mn) * 0.125f);
      s[j][r] = pv;
      psum += pv;
    }
    l_[r] = l_[r] * alpha + psum;  // per-lane partial; reduced in epilogue
#pragma unroll
    for (int j = 0; j < 4; j++) o[j][r] *= alpha;
  }
  // P: C-layout regs -> LDS (wave-private) -> A-layout frags
#pragma unroll
  for (int j = 0; j < 4; j++)
#pragma unroll
    for (int r = 0; r < 4; r++)
      myP[(lq * 4 + r) * KSTR + j * 16 + lr] = f2bf_rtz(s[j][r]);
  __asm__ volatile("s_waitcnt lgkmcnt(0)" ::: "memory");  // wave-level fence
  bf16x8 pf0 = *(const bf16x8*)&myP[lr * KSTR + lq * 8];
  bf16x8 pf1 = *(const bf16x8*)&myP[lr * KSTR + 32 + lq * 8];
#pragma unroll
  for (int jd = 0; jd < 4; jd++) {
    bf16x8 vf0 = *(const bf16x8*)&Vs[(jd * 16 + lr) * KSTR + lq * 8];
    bf16x8 vf1 = *(const bf16x8*)&Vs[(jd * 16 + lr) * KSTR + 32 + lq * 8];
    o[jd] = MFMA16(pf0, vf0, o[jd]);
    o[jd] = MFMA16(pf1, vf1, o[jd]);
  }
}

__global__ __launch_bounds__(256, 4) void attn_paired(u16* __restrict__ qkv) {
  __shared__ u16 Ks[64 * KSTR];
  __shared__ u16 Vs[64 * KSTR];
  __shared__ u16 Ps[4][16 * KSTR];  // per-wave; halves use it sequentially

  const int tid = threadIdx.x;
  const int w = tid >> 6, lane = tid & 63;
  const int lq = lane >> 4, lr = lane & 15;
  const int bh = blockIdx.x, p = blockIdx.y;
  const int h = bh & (NH - 1), b = bh >> 4;
  const int qt0 = p, qt1 = (SL / 64 - 1) - p;

  u16* base = qkv + (size_t)b * SL * N3;
  // staging: this thread owns key=skey, d-chunks [sd0,sd0+8) and +32
  const int skey = tid & 63, sd0 = (tid >> 6) * 8;
  const u16* kvrow = base + (size_t)skey * N3 + NE + h * HD + sd0;  // K plane

  bf16x8 qf[2][2];
#pragma unroll
  for (int half = 0; half < 2; half++) {
    int qt = half ? qt1 : qt0;
    const u16* qrow = base + (size_t)(qt * 64 + w * 16 + lr) * N3 + h * HD;
    qf[half][0] = *(const bf16x8*)(qrow + lq * 8);
    qf[half][1] = *(const bf16x8*)(qrow + 32 + lq * 8);
  }

  const f32x4 fzero = {0.f, 0.f, 0.f, 0.f};
  f32x4 o[2][4];
  float m_[2][4], l_[2][4];
#pragma unroll
  for (int half = 0; half < 2; half++)
#pragma unroll
    for (int r = 0; r < 4; r++) {
      o[half][r] = fzero;
      m_[half][r] = -1e30f;
      l_[half][r] = 0.f;
    }

  // prologue: tile 0 into static regs (K: k0,k1; V: v0,v1)
  int4 k0 = *(const int4*)kvrow;
  int4 k1 = *(const int4*)(kvrow + 32);
  int4 v0 = *(const int4*)(kvrow + NE);
  int4 v1 = *(const int4*)(kvrow + NE + 32);

  const int ktend = qt1 + 1;
  for (int kt = 0; kt < ktend; kt++) {
    __syncthreads();  // readers of tile kt-1 done (also drains prefetch)
    // regs -> LDS: K row-major, V transposed
    *(int4*)&Ks[skey * KSTR + sd0] = k0;
    *(int4*)&Ks[skey * KSTR + sd0 + 32] = k1;
    {
      union { int4 v; u16 u[8]; } t0, t1;
      t0.v = v0; t1.v = v1;
#pragma unroll
      for (int j = 0; j < 8; j++) {
        Vs[(sd0 + j) * KSTR + skey] = t0.u[j];
        Vs[(sd0 + 32 + j) * KSTR + skey] = t1.u[j];
      }
    }
    __syncthreads();  // LDS ready

    if (kt + 1 < ktend) {  // prefetch kt+1; latency hidden by compute below
      const u16* nr = kvrow + (size_t)(kt + 1) * 64 * N3;
      k0 = *(const int4*)nr;
      k1 = *(const int4*)(nr + 32);
      v0 = *(const int4*)(nr + NE);
      v1 = *(const int4*)(nr + NE + 32);
    }

    attn_step(qf[1][0], qf[1][1], Ks, Vs, &Ps[w][0], kt == qt1, w, lq, lr,
              o[1], m_[1], l_[1]);
    if (kt <= qt0)
      attn_step(qf[0][0], qf[0][1], Ks, Vs, &Ps[w][0], kt == qt0, w, lq, lr,
                o[0], m_[0], l_[0]);
  }

  // epilogue: reduce per-lane l partials across the 16 col-lanes, write Y
  // over the Q slot (rows are block-private -> in-place safe)
#pragma unroll
  for (int half = 0; half < 2; half++) {
    int qt = half ? qt1 : qt0;
#pragma unroll
    for (int r = 0; r < 4; r++) {
      float lsum = l_[half][r];
#pragma unroll
      for (int off = 1; off < 16; off <<= 1) lsum += __shfl_xor(lsum, off, 16);
      float inv = 1.0f / lsum;
      int srow = qt * 64 + w * 16 + lq * 4 + r;
      u16* yrow = base + (size_t)srow * N3 + h * HD;
#pragma unroll
      for (int j = 0; j < 4; j++) yrow[j * 16 + lr] = f2bf(o[half][j][r] * inv);
    }
  }
}

// ---------------- host launch ----------------
extern "C" void kernel_launch(void* const* d_in, const int* in_sizes, int n_in,
                              void* d_out, int out_size, void* d_ws,
                              size_t ws_size, hipStream_t stream) {
  // inputs (fp32 / int32): x, mask(ignored - analytic causal), Wqkv, bqkv,
  // Wo, bo
  const float* x    = (const float*)d_in[0];
  const float* Wqkv = (const float*)d_in[2];
  const float* bqkv = (const float*)d_in[3];
  const float* Wo   = (const float*)d_in[4];
  const float* bo   = (const float*)d_in[5];

  u16* WqkvT  = (u16*)d_ws;                       // [3072,1024] bf16
  u16* WoT    = WqkvT + (size_t)N3 * NE;          // [1024,1024] bf16
  u16* xb     = WoT + (size_t)NE * NE;            // [8192,1024] bf16
  u16* qkvbuf = xb + (size_t)BS * SL * NE;        // [8192,3072] bf16

  convert_x<<<(BS * SL * NE) / (256 * 8), 256, 0, stream>>>(x, xb);
  transpose_w<<<dim3(N3 / 32, NE / 32), dim3(32, 8), 0, stream>>>(Wqkv, WqkvT,
                                                                  NE, N3);
  transpose_w<<<dim3(NE / 32, NE / 32), dim3(32, 8), 0, stream>>>(Wo, WoT, NE,
                                                                  NE);
  gemm_bt<0><<<dim3(N3 / 128, (BS * SL) / 128), 256, 0, stream>>>(
      xb, WqkvT, bqkv, qkvbuf, BS * SL, N3, NE, NE);
  attn_paired<<<dim3(BS * NH, SL / 128), 256, 0, stream>>>(qkvbuf);
  gemm_bt<1><<<dim3(NE / 128, (BS * SL) / 128), 256, 0, stream>>>(
      qkvbuf, WoT, bo, d_out, BS * SL, NE, NE, N3);
}

// Round 9
// 332.063 us; speedup vs baseline: 1.7414x; 1.0309x over previous
//
#include <hip/hip_runtime.h>

#define BS 4
#define SL 2048
#define NE 1024
#define NH 16
#define HD 64
#define N3 3072

typedef __attribute__((ext_vector_type(8))) __bf16 bf16x8;
typedef __attribute__((ext_vector_type(4))) float f32x4;
typedef unsigned short u16;

__device__ __forceinline__ u16 f2bf(float f) {
  union { float f; unsigned int u; } v; v.f = f;
  unsigned int r = v.u + 0x7FFFu + ((v.u >> 16) & 1u);
  return (u16)(r >> 16);
}
__device__ __forceinline__ u16 f2bf_rtz(float f) {
  union { float f; unsigned int u; } v; v.f = f;
  return (u16)(v.u >> 16);
}

// global -> LDS direct 16B copy. LDS dest is WAVE-UNIFORM base; HW adds
// lane*16. Global address is per-lane.
__device__ __forceinline__ void gld16(const void* g, void* l) {
#if __has_builtin(__builtin_amdgcn_global_load_lds)
  __builtin_amdgcn_global_load_lds(
      (const __attribute__((address_space(1))) unsigned int*)g,
      (__attribute__((address_space(3))) unsigned int*)l, 16, 0, 0);
#else
  *(int4*)((char*)l + (size_t)(threadIdx.x & 63) * 16) = *(const int4*)g;
#endif
}

// ---------------- x fp32 -> bf16 ----------------
__global__ void convert_x(const float* __restrict__ x, u16* __restrict__ xb) {
  int i = (blockIdx.x * 256 + threadIdx.x) * 8;
  float4 f0 = *(const float4*)(x + i);
  float4 f1 = *(const float4*)(x + i + 4);
  union { int4 v; u16 h[8]; } p;
  p.h[0] = f2bf(f0.x); p.h[1] = f2bf(f0.y);
  p.h[2] = f2bf(f0.z); p.h[3] = f2bf(f0.w);
  p.h[4] = f2bf(f1.x); p.h[5] = f2bf(f1.y);
  p.h[6] = f2bf(f1.z); p.h[7] = f2bf(f1.w);
  *(int4*)(xb + i) = p.v;
}

// ---------------- W transpose+convert: Wt[n*K+k] = bf16(W[k*N+n]) ----------
__global__ void transpose_w(const float* __restrict__ W, u16* __restrict__ Wt,
                            int K, int N) {
  __shared__ u16 tile[32][33];
  int bn = blockIdx.x * 32, bk = blockIdx.y * 32;
  int tx = threadIdx.x, ty = threadIdx.y;  // blockDim = (32, 8)
  for (int r = 0; r < 32; r += 8)
    tile[ty + r][tx] = f2bf(W[(size_t)(bk + ty + r) * N + bn + tx]);
  __syncthreads();
  for (int r = 0; r < 32; r += 8)
    Wt[(size_t)(bn + ty + r) * K + bk + tx] = tile[tx][ty + r];
}

// ---------------- GEMM: C[M,N] = A[M,K] @ Bt[N,K]^T + bias[N] ---------------
// A, Bt bf16 staged via global_load_lds width=16. C32: store fp32 else bf16.
template <int C32>
__global__ __launch_bounds__(256) void gemm_bt(
    const u16* __restrict__ A, const u16* __restrict__ Bt,
    const float* __restrict__ bias, void* __restrict__ C, int M, int N, int K,
    int lda) {
  __shared__ u16 As[128 * 32];
  __shared__ u16 Bs[128 * 32];

  const int tid = threadIdx.x;
  const int wave = tid >> 6, lane = tid & 63;
  const int lq = lane >> 4, lr = lane & 15;
  const int m0 = blockIdx.y * 128, n0 = blockIdx.x * 128;
  const int wm = (wave & 1) * 64, wn = (wave >> 1) * 64;

  const f32x4 fzero = {0.f, 0.f, 0.f, 0.f};
  f32x4 acc[4][4];
#pragma unroll
  for (int i = 0; i < 4; i++)
#pragma unroll
    for (int j = 0; j < 4; j++) acc[i][j] = fzero;

  for (int k0 = 0; k0 < K; k0 += 32) {
    __syncthreads();  // previous iteration's LDS readers are done
#pragma unroll
    for (int t = 0; t < 2; t++) {
      int chunk = wave * 2 + t;  // 1 KB chunk = 16 rows x 64 B
      const u16* ga = A + (size_t)(m0 + chunk * 16 + (lane >> 2)) * lda + k0 +
                      (lane & 3) * 8;
      gld16(ga, &As[chunk * 512]);
      const u16* gb = Bt + (size_t)(n0 + chunk * 16 + (lane >> 2)) * K + k0 +
                      (lane & 3) * 8;
      gld16(gb, &Bs[chunk * 512]);
    }
    __syncthreads();  // drains vmcnt (global_load_lds) + lgkm

    bf16x8 af[4], bfr[4];
#pragma unroll
    for (int i = 0; i < 4; i++)
      af[i] = *(const bf16x8*)&As[(wm + i * 16 + lr) * 32 + lq * 8];
#pragma unroll
    for (int j = 0; j < 4; j++)
      bfr[j] = *(const bf16x8*)&Bs[(wn + j * 16 + lr) * 32 + lq * 8];
#pragma unroll
    for (int i = 0; i < 4; i++)
#pragma unroll
      for (int j = 0; j < 4; j++)
        acc[i][j] = __builtin_amdgcn_mfma_f32_16x16x32_bf16(af[i], bfr[j],
                                                            acc[i][j], 0, 0, 0);
  }

  // Epilogue. C/D layout: col = lane&15, row = (lane>>4)*4 + reg.
#pragma unroll
  for (int j = 0; j < 4; j++) {
    int col = n0 + wn + j * 16 + lr;
    float bv = bias[col];
#pragma unroll
    for (int i = 0; i < 4; i++) {
#pragma unroll
      for (int r = 0; r < 4; r++) {
        int row = m0 + wm + i * 16 + lq * 4 + r;
        float val = acc[i][j][r] + bv;
        if (C32) ((float*)C)[(size_t)row * N + col] = val;
        else     ((u16*)C)[(size_t)row * N + col]   = f2bf(val);
      }
    }
  }
}

// ---------------- Flash attention (causal), paired q-tiles ----------------
// Block (bh, p): q-tiles {p, 31-p} -> exactly 33 half-tile steps per block.
// 16 p-blocks of one (b,h) share linear-id mod 8 -> same XCD -> K/V L2 reuse
// (r7: FETCH 34.6MB vs 540MB demand).
// Pipelining: K(kt+1) via async global_load_lds into the other K buffer
// (ZERO register cost — r8's 16 prefetch regs blew the (256,4) 128-reg
// unified budget: WRITE 16->114MB scratch spill). V(kt+1) in static named
// regs v0/v1 only (8 regs; V needs the transpose so it must cross registers).
// Both issued right after the LDS-ready barrier; the whole compute phase
// hides them; next iteration's first __syncthreads drains.
// K LDS layout (gld16 can't write padded rows): [key][32-elem d-half],
// halves at +2048 elems, d-block XOR-swizzled by key&3 via the SOURCE
// address (r6-verified). V/P: padded KSTR rows (r7/r8-verified).
#define KSTR 72  // 64 + 8 pad elems (rows 16B aligned)
#define MFMA16(a, b, c) __builtin_amdgcn_mfma_f32_16x16x32_bf16(a, b, c, 0, 0, 0)

__device__ __forceinline__ void attn_step(const bf16x8& q0, const bf16x8& q1,
                                          const u16* __restrict__ Kb,
                                          const u16* __restrict__ Vs,
                                          u16* __restrict__ myP, bool diag,
                                          int w, int lq, int lr,
                                          f32x4 (&o)[4], float (&m_)[4],
                                          float (&l_)[4]) {
  const f32x4 fzero = {0.f, 0.f, 0.f, 0.f};
  const int swk = lr & 3;
  f32x4 s[4];
#pragma unroll
  for (int j = 0; j < 4; j++) {
    int kr = j * 16 + lr;
    bf16x8 kf0 = *(const bf16x8*)&Kb[kr * 32 + ((lq ^ swk) * 8)];
    bf16x8 kf1 = *(const bf16x8*)&Kb[2048 + kr * 32 + ((lq ^ swk) * 8)];
    f32x4 z = MFMA16(q0, kf0, fzero);
    s[j] = MFMA16(q1, kf1, z);
  }
  if (diag) {  // local col = j*16+lr, local row = w*16+lq*4+r (raw scores)
#pragma unroll
    for (int j = 0; j < 4; j++)
#pragma unroll
      for (int r = 0; r < 4; r++)
        if (j * 16 + lr > w * 16 + lq * 4 + r) s[j][r] = -1e30f;
  }
  // online softmax on RAW scores; 1/sqrt(HD)=0.125 folded into exp args
#pragma unroll
  for (int r = 0; r < 4; r++) {
    float mt = fmaxf(fmaxf(s[0][r], s[1][r]), fmaxf(s[2][r], s[3][r]));
#pragma unroll
    for (int off = 1; off < 16; off <<= 1)
      mt = fmaxf(mt, __shfl_xor(mt, off, 16));
    float mn = fmaxf(m_[r], mt);
    float alpha = __expf((m_[r] - mn) * 0.125f);
    m_[r] = mn;
    float psum = 0.f;
#pragma unroll
    for (int j = 0; j < 4; j++) {
      float pv = __expf((s[j][r] - mn) * 0.125f);
      s[j][r] = pv;
      psum += pv;
    }
    l_[r] = l_[r] * alpha + psum;  // per-lane partial; reduced in epilogue
#pragma unroll
    for (int j = 0; j < 4; j++) o[j][r] *= alpha;
  }
  // P: C-layout regs -> LDS (wave-private) -> A-layout frags
#pragma unroll
  for (int j = 0; j < 4; j++)
#pragma unroll
    for (int r = 0; r < 4; r++)
      myP[(lq * 4 + r) * KSTR + j * 16 + lr] = f2bf_rtz(s[j][r]);
  __asm__ volatile("s_waitcnt lgkmcnt(0)" ::: "memory");  // wave-level fence
  bf16x8 pf0 = *(const bf16x8*)&myP[lr * KSTR + lq * 8];
  bf16x8 pf1 = *(const bf16x8*)&myP[lr * KSTR + 32 + lq * 8];
#pragma unroll
  for (int jd = 0; jd < 4; jd++) {
    bf16x8 vf0 = *(const bf16x8*)&Vs[(jd * 16 + lr) * KSTR + lq * 8];
    bf16x8 vf1 = *(const bf16x8*)&Vs[(jd * 16 + lr) * KSTR + 32 + lq * 8];
    o[jd] = MFMA16(pf0, vf0, o[jd]);
    o[jd] = MFMA16(pf1, vf1, o[jd]);
  }
}

__global__ __launch_bounds__(256, 4) void attn_paired(u16* __restrict__ qkv) {
  __shared__ u16 Ks[2][4096];       // [key*32 + swz d-blk], d-half at +2048
  __shared__ u16 Vs[64 * KSTR];     // padded, transposed
  __shared__ u16 Ps[4][16 * KSTR];  // per-wave; halves use it sequentially

  const int tid = threadIdx.x;
  const int w = tid >> 6, lane = tid & 63;
  const int lq = lane >> 4, lr = lane & 15;
  const int bh = blockIdx.x, p = blockIdx.y;
  const int h = bh & (NH - 1), b = bh >> 4;
  const int qt0 = p, qt1 = (SL / 64 - 1) - p;

  u16* base = qkv + (size_t)b * SL * N3;
  const u16* kbase = base + NE + h * HD;  // K plane; V plane at +NE

  // K gld16 staging: wave w stages chunks {2w,2w+1}; chunk = half*4 + kgrp
  const int kg_key = lane >> 2;                        // key within 16-group
  const int kg_blk = (lane & 3) ^ (kg_key & 3);        // source d-block (swz)
  // V staging: thread owns key=skey, d-chunks [sd0,sd0+8) and +32
  const int skey = tid & 63, sd0 = (tid >> 6) * 8;
  const u16* vrow0 = base + (size_t)skey * N3 + 2 * NE + h * HD + sd0;

#define KPRE(buf, key0)                                                     \
  {                                                                         \
    _Pragma("unroll") for (int t = 0; t < 2; t++) {                         \
      int chunk = w * 2 + t, half = chunk >> 2, kgrp = chunk & 3;           \
      const u16* g = kbase + (size_t)((key0) + kgrp * 16 + kg_key) * N3 +   \
                     half * 32 + kg_blk * 8;                                \
      gld16(g, &Ks[buf][half * 2048 + kgrp * 512]);                         \
    }                                                                       \
  }

  bf16x8 qf[2][2];
#pragma unroll
  for (int half = 0; half < 2; half++) {
    int qt = half ? qt1 : qt0;
    const u16* qrow = base + (size_t)(qt * 64 + w * 16 + lr) * N3 + h * HD;
    qf[half][0] = *(const bf16x8*)(qrow + lq * 8);
    qf[half][1] = *(const bf16x8*)(qrow + 32 + lq * 8);
  }

  const f32x4 fzero = {0.f, 0.f, 0.f, 0.f};
  f32x4 o[2][4];
  float m_[2][4], l_[2][4];
#pragma unroll
  for (int half = 0; half < 2; half++)
#pragma unroll
    for (int r = 0; r < 4; r++) {
      o[half][r] = fzero;
      m_[half][r] = -1e30f;
      l_[half][r] = 0.f;
    }

  // prologue: K(0) async -> Ks[0]; V(0) -> static regs
  KPRE(0, 0);
  int4 v0 = *(const int4*)vrow0;
  int4 v1 = *(const int4*)(vrow0 + 32);

  const int ktend = qt1 + 1;
  for (int kt = 0; kt < ktend; kt++) {
    __syncthreads();  // readers of tile kt-1 done; drains K(kt) async + v regs
    {  // V(kt) regs -> LDS transposed
      union { int4 v; u16 u[8]; } t0, t1;
      t0.v = v0; t1.v = v1;
#pragma unroll
      for (int j = 0; j < 8; j++) {
        Vs[(sd0 + j) * KSTR + skey] = t0.u[j];
        Vs[(sd0 + 32 + j) * KSTR + skey] = t1.u[j];
      }
    }
    __syncthreads();  // LDS(kt) ready

    if (kt + 1 < ktend) {  // prefetch kt+1; hidden by compute below
      KPRE((kt + 1) & 1, (kt + 1) * 64);
      const u16* nv = vrow0 + (size_t)(kt + 1) * 64 * N3;
      v0 = *(const int4*)nv;
      v1 = *(const int4*)(nv + 32);
    }

    const u16* Kb = &Ks[kt & 1][0];
    attn_step(qf[1][0], qf[1][1], Kb, Vs, &Ps[w][0], kt == qt1, w, lq, lr,
              o[1], m_[1], l_[1]);
    if (kt <= qt0)
      attn_step(qf[0][0], qf[0][1], Kb, Vs, &Ps[w][0], kt == qt0, w, lq, lr,
                o[0], m_[0], l_[0]);
  }

  // epilogue: reduce per-lane l partials across the 16 col-lanes, write Y
  // over the Q slot (rows are block-private -> in-place safe)
#pragma unroll
  for (int half = 0; half < 2; half++) {
    int qt = half ? qt1 : qt0;
#pragma unroll
    for (int r = 0; r < 4; r++) {
      float lsum = l_[half][r];
#pragma unroll
      for (int off = 1; off < 16; off <<= 1) lsum += __shfl_xor(lsum, off, 16);
      float inv = 1.0f / lsum;
      int srow = qt * 64 + w * 16 + lq * 4 + r;
      u16* yrow = base + (size_t)srow * N3 + h * HD;
#pragma unroll
      for (int j = 0; j < 4; j++) yrow[j * 16 + lr] = f2bf(o[half][j][r] * inv);
    }
  }
}

// ---------------- host launch ----------------
extern "C" void kernel_launch(void* const* d_in, const int* in_sizes, int n_in,
                              void* d_out, int out_size, void* d_ws,
                              size_t ws_size, hipStream_t stream) {
  // inputs (fp32 / int32): x, mask(ignored - analytic causal), Wqkv, bqkv,
  // Wo, bo
  const float* x    = (const float*)d_in[0];
  const float* Wqkv = (const float*)d_in[2];
  const float* bqkv = (const float*)d_in[3];
  const float* Wo   = (const float*)d_in[4];
  const float* bo   = (const float*)d_in[5];

  u16* WqkvT  = (u16*)d_ws;                       // [3072,1024] bf16
  u16* WoT    = WqkvT + (size_t)N3 * NE;          // [1024,1024] bf16
  u16* xb     = WoT + (size_t)NE * NE;            // [8192,1024] bf16
  u16* qkvbuf = xb + (size_t)BS * SL * NE;        // [8192,3072] bf16

  convert_x<<<(BS * SL * NE) / (256 * 8), 256, 0, stream>>>(x, xb);
  transpose_w<<<dim3(N3 / 32, NE / 32), dim3(32, 8), 0, stream>>>(Wqkv, WqkvT,
                                                                  NE, N3);
  transpose_w<<<dim3(NE / 32, NE / 32), dim3(32, 8), 0, stream>>>(Wo, WoT, NE,
                                                                  NE);
  gemm_bt<0><<<dim3(N3 / 128, (BS * SL) / 128), 256, 0, stream>>>(
      xb, WqkvT, bqkv, qkvbuf, BS * SL, N3, NE, NE);
  attn_paired<<<dim3(BS * NH, SL / 128), 256, 0, stream>>>(qkvbuf);
  gemm_bt<1><<<dim3(NE / 128, (BS * SL) / 128), 256, 0, stream>>>(
      qkvbuf, WoT, bo, d_out, BS * SL, NE, NE, N3);
}